// Round 5
// baseline (1576.357 us; speedup 1.0000x reference)
//
#include <hip/hip_runtime.h>

// ---------------------------------------------------------------------------
// MoE forward: gating MLP + 8 dense experts + gate-weighted combine.
// All matmuls via mfma_f32_16x16x32_f16 (fp32 accum).
// GEMM: BM=256, BN=128, BK=64, THREE buffers per operand (144KB LDS).
// 2 phases per K-tile, 16 MFMA each (wave-tile 128x32, 8 waves 2Mx4N).
// Phase-A(t): read A(mh0)+all B of tile t | stage A(t+2).
// Phase-B(t): read A(mh1)               | stage B(t+3) | vmcnt(8,6,0).
// Issue->wait lead = 3 full phases (> L3/HBM latency). FIFO-verified.
// LDS swizzle byte^=((row&7)<<4); inverse pre-applied to global source
// (rule #21: gload_lds writes linearly).
// ---------------------------------------------------------------------------

#define DI __device__ __forceinline__

typedef _Float16 f16;
typedef _Float16 f16x8 __attribute__((ext_vector_type(8)));
typedef float f32x4 __attribute__((ext_vector_type(4)));

constexpr int BSZ  = 8192;
constexpr int IND  = 1024;
constexpr int HID  = 4096;
constexpr int OUTD = 1024;
constexpr int NE   = 8;
constexpr int HGD  = 2048;

// ---------------- fp32 -> fp16 vectorized convert (8 elems/thread) ---------
__global__ __launch_bounds__(256) void conv_f32_f16_kernel(
    const float* __restrict__ in, f16* __restrict__ out)
{
    size_t i = ((size_t)blockIdx.x * 256 + threadIdx.x) * 8;
    const float4* p = (const float4*)(in + i);
    float4 a = p[0], b = p[1];
    f16x8 v = {(f16)a.x, (f16)a.y, (f16)a.z, (f16)a.w,
               (f16)b.x, (f16)b.y, (f16)b.z, (f16)b.w};
    *(f16x8*)(out + i) = v;
}

// ------------- transpose + convert: W[K][N] f32 -> Wt[N][K] f16 ------------
__global__ __launch_bounds__(256) void transpose_f32_f16_kernel(
    const float* __restrict__ W, f16* __restrict__ Wt, int K, int N)
{
    __shared__ float t[64][65];
    int n0 = blockIdx.x * 64, k0 = blockIdx.y * 64;
    int tx = threadIdx.x & 63, ty = threadIdx.x >> 6;
#pragma unroll
    for (int i = 0; i < 16; i++) {
        int k = i * 4 + ty;
        t[k][tx] = W[(size_t)(k0 + k) * N + n0 + tx];
    }
    __syncthreads();
#pragma unroll
    for (int i = 0; i < 16; i++) {
        int n = i * 4 + ty;
        Wt[(size_t)(n0 + n) * K + k0 + tx] = (f16)t[tx][n];
    }
}

// ---------------- async global->LDS (16B per lane, wave-uniform dest) ------
DI void gload_lds16(const void* g, void* l)
{
    typedef const __attribute__((address_space(1))) unsigned int as1_t;
    typedef __attribute__((address_space(3))) unsigned int as3_t;
    __builtin_amdgcn_global_load_lds(
        (as1_t*)(unsigned long long)(__SIZE_TYPE__)g,
        (as3_t*)(unsigned int)(__SIZE_TYPE__)l,
        16, 0, 0);
}

// sync building blocks (rule #18: sched_barrier after lgkmcnt before MFMA)
#define SYNC_HEAD                                                              \
    __builtin_amdgcn_sched_barrier(0);                                         \
    __builtin_amdgcn_s_barrier();                                              \
    asm volatile("s_waitcnt lgkmcnt(0)" ::: "memory");                         \
    __builtin_amdgcn_sched_barrier(0);
#define SYNC_HEAD_T8                                                           \
    __builtin_amdgcn_sched_barrier(0);                                         \
    asm volatile("s_waitcnt lgkmcnt(8)");                                      \
    __builtin_amdgcn_s_barrier();                                              \
    asm volatile("s_waitcnt lgkmcnt(0)" ::: "memory");                         \
    __builtin_amdgcn_sched_barrier(0);
#define SYNC_TAIL                                                              \
    __builtin_amdgcn_sched_barrier(0);                                         \
    __builtin_amdgcn_s_barrier();                                              \
    asm volatile("" ::: "memory");

// ---------------------------------------------------------------------------
// Triple-buffered fine-phase GEMM: C[M,N] = op(A[M,K] @ Bt[N,K]^T + bias[N])
// Requires NT = K/64 with NT % 3 == 1 (holds for K=1024, 4096).
// ---------------------------------------------------------------------------

#define PHA(B, T)                                                              \
  {                                                                            \
    _Pragma("unroll") for (int f = 0; f < 4; f++)                              \
    _Pragma("unroll") for (int kc = 0; kc < 2; kc++)                           \
        av[f][kc] = *(const f16x8*)(sAc + (B) * ATILE + (offA0[f] ^ (kc << 6))); \
    _Pragma("unroll") for (int g = 0; g < 2; g++)                              \
    _Pragma("unroll") for (int kc = 0; kc < 2; kc++)                           \
        bv[g][kc] = *(const f16x8*)(sBc + (B) * BTILE + (offB0[g] ^ (kc << 6))); \
    if ((T) + 2 < NT) {                                                        \
        stA(((B) + 2) % 3, 0, (T) + 2); stA(((B) + 2) % 3, 1, (T) + 2);        \
        stA(((B) + 2) % 3, 2, (T) + 2); stA(((B) + 2) % 3, 3, (T) + 2);        \
    }                                                                          \
    SYNC_HEAD_T8                                                               \
    __builtin_amdgcn_s_setprio(1);                                             \
    _Pragma("unroll") for (int f = 0; f < 4; f++)                              \
    _Pragma("unroll") for (int g = 0; g < 2; g++)                              \
    _Pragma("unroll") for (int kc = 0; kc < 2; kc++)                           \
        acc[f][g] = __builtin_amdgcn_mfma_f32_16x16x32_f16(                    \
            av[f][kc], bv[g][kc], acc[f][g], 0, 0, 0);                         \
    __builtin_amdgcn_s_setprio(0);                                             \
    SYNC_TAIL                                                                  \
  }

#define PHB(B, T)                                                              \
  {                                                                            \
    _Pragma("unroll") for (int f = 0; f < 4; f++)                              \
    _Pragma("unroll") for (int kc = 0; kc < 2; kc++)                           \
        av[f][kc] = *(const f16x8*)(sAc + (B) * ATILE + 8192 + (offA0[f] ^ (kc << 6))); \
    if ((T) + 3 < NT) { stB((B), 0, (T) + 3); stB((B), 1, (T) + 3); }          \
    SYNC_HEAD                                                                  \
    __builtin_amdgcn_s_setprio(1);                                             \
    _Pragma("unroll") for (int f = 0; f < 4; f++)                              \
    _Pragma("unroll") for (int g = 0; g < 2; g++)                              \
    _Pragma("unroll") for (int kc = 0; kc < 2; kc++)                           \
        acc[4 + f][g] = __builtin_amdgcn_mfma_f32_16x16x32_f16(                \
            av[f][kc], bv[g][kc], acc[4 + f][g], 0, 0, 0);                     \
    __builtin_amdgcn_s_setprio(0);                                             \
    if ((T) <= NT - 4)      { asm volatile("s_waitcnt vmcnt(8)"); }            \
    else if ((T) == NT - 3) { asm volatile("s_waitcnt vmcnt(6)"); }            \
    else if ((T) == NT - 2) { asm volatile("s_waitcnt vmcnt(0)"); }            \
    SYNC_TAIL                                                                  \
  }

template <bool RELU, bool GATE, bool OUT_F16, bool ACCUM>
__global__ __launch_bounds__(512, 2) void gemm3b_kernel(
    const f16* __restrict__ A, const f16* __restrict__ Bt,
    const float* __restrict__ bias, const float* __restrict__ gate,
    void* __restrict__ Cptr, int M, int N, int K)
{
    constexpr int BM = 256, BN = 128, BK = 64;
    constexpr int ATILE = BM * BK * 2;   // 32768 B
    constexpr int BTILE = BN * BK * 2;   // 16384 B
    __shared__ __align__(16) f16 sA[3][BM * BK];
    __shared__ __align__(16) f16 sB[3][BN * BK];
    const char* sAc = (const char*)sA;
    const char* sBc = (const char*)sB;

    const int tid = threadIdx.x, wid = tid >> 6, lane = tid & 63;
    const int wm = wid >> 2, wn = wid & 3;

    // bijective XCD swizzle (all grids here are multiples of 8)
    const int nwg = gridDim.x, bid = blockIdx.x;
    const int wg = (bid & 7) * (nwg >> 3) + (bid >> 3);
    const int gx = N / BN;
    const size_t bm = (size_t)(wg / gx) * BM;
    const size_t bn = (size_t)(wg % gx) * BN;

    f32x4 acc[8][2] = {};

    // stage source (inverse swizzle on global source, rule #21)
    const int rho  = tid >> 3;
    const int slot = (((tid & 7) << 4) ^ (((tid >> 3) & 7) << 4));
    const f16* pA = A  + (bm + rho) * (size_t)K + (slot >> 1);
    const f16* pB = Bt + (bn + rho) * (size_t)K + (slot >> 1);

    auto stA = [&](int b, int q, int T) {
        gload_lds16(pA + ((size_t)q * 64) * K + (size_t)T * BK,
                    (char*)sAc + b * ATILE + q * 8192 + wid * 1024);
    };
    auto stB = [&](int b, int q, int T) {
        gload_lds16(pB + ((size_t)q * 64) * K + (size_t)T * BK,
                    (char*)sBc + b * BTILE + q * 8192 + wid * 1024);
    };

    // fragment read offsets (swizzled); kc toggles byte bit 6; mh1 = +8192
    int offA0[4], offB0[2];
    const int ks4 = (lane >> 4) << 4;
#pragma unroll
    for (int f = 0; f < 4; f++) {
        int r = wm * 128 + f * 16 + (lane & 15);
        offA0[f] = r * 128 + (ks4 ^ ((r & 7) << 4));
    }
#pragma unroll
    for (int g = 0; g < 2; g++) {
        int r = wn * 32 + g * 16 + (lane & 15);
        offB0[g] = r * 128 + (ks4 ^ ((r & 7) << 4));
    }

    f16x8 av[4][2], bv[2][2];
    const int NT = K / BK;   // 16 or 64; NT % 3 == 1

    // prologue: A0,B0,A1,B1,B2 staged (14 calls); drain A0+B0 -> vmcnt(8)
    stA(0, 0, 0); stA(0, 1, 0); stA(0, 2, 0); stA(0, 3, 0);
    stB(0, 0, 0); stB(0, 1, 0);
    stA(1, 0, 1); stA(1, 1, 1); stA(1, 2, 1); stA(1, 3, 1);
    stB(1, 0, 1); stB(1, 1, 1);
    stB(2, 0, 2); stB(2, 1, 2);
    asm volatile("s_waitcnt vmcnt(8)");
    __builtin_amdgcn_s_barrier();
    asm volatile("" ::: "memory");

    // t=0 peel (buf0), then 3-tile groups with constexpr buffer indices
    PHA(0, 0) PHB(0, 0)
    for (int t = 1; t < NT; t += 3) {
        PHA(1, t)     PHB(1, t)
        PHA(2, t + 1) PHB(2, t + 1)
        PHA(0, t + 2) PHB(0, t + 2)
    }

    // epilogue: C/D layout col=lane&15, row=(lane>>4)*4+reg  [m89-verified]
    const size_t row0 = bm + (size_t)wm * 128;
    const int col0 = (int)bn + wn * 32;
    const int c0 = lane & 15, r0 = (lane >> 4) * 4;
#pragma unroll
    for (int fm = 0; fm < 8; fm++) {
#pragma unroll
        for (int r = 0; r < 4; r++) {
            const size_t row = row0 + fm * 16 + r0 + r;
            float g = 1.0f;
            if constexpr (GATE) g = gate[row * NE];
#pragma unroll
            for (int n = 0; n < 2; n++) {
                const size_t col = (size_t)col0 + n * 16 + c0;
                float v = acc[fm][n][r] + bias[col];
                if constexpr (RELU) v = fmaxf(v, 0.0f);
                if constexpr (GATE) v *= g;
                if constexpr (OUT_F16) {
                    ((f16*)Cptr)[row * (size_t)N + col] = (f16)v;
                } else {
                    float* p = (float*)Cptr + row * (size_t)N + col;
                    *p = ACCUM ? (*p + v) : v;
                }
            }
        }
    }
}

// --------- gating head: logits = gh@gw2 + gb2, softmax -> gates fp32 -------
__global__ __launch_bounds__(256) void gate_softmax_kernel(
    const f16* __restrict__ gh, const float* __restrict__ gw2,
    const float* __restrict__ gb2, float* __restrict__ gates)
{
    const int row  = blockIdx.x * 4 + (threadIdx.x >> 6);
    const int lane = threadIdx.x & 63;
    const f16* r = gh + (size_t)row * HGD;
    float acc[NE] = {};
    for (int k = lane; k < HGD; k += 64) {
        float h = (float)r[k];
        const float* w = gw2 + (size_t)k * NE;
#pragma unroll
        for (int e = 0; e < NE; e++) acc[e] = fmaf(h, w[e], acc[e]);
    }
#pragma unroll
    for (int off = 32; off > 0; off >>= 1)
#pragma unroll
        for (int e = 0; e < NE; e++) acc[e] += __shfl_down(acc[e], off, 64);
    if (lane == 0) {
        float l[NE], m = -1e30f;
#pragma unroll
        for (int e = 0; e < NE; e++) { l[e] = acc[e] + gb2[e]; m = fmaxf(m, l[e]); }
        float s = 0.f;
#pragma unroll
        for (int e = 0; e < NE; e++) { l[e] = expf(l[e] - m); s += l[e]; }
        float inv = 1.0f / s;
#pragma unroll
        for (int e = 0; e < NE; e++) gates[(size_t)row * NE + e] = l[e] * inv;
    }
}

// ---------------------------------------------------------------------------
extern "C" void kernel_launch(void* const* d_in, const int* in_sizes, int n_in,
                              void* d_out, int out_size, void* d_ws, size_t ws_size,
                              hipStream_t stream)
{
    const float* x   = (const float*)d_in[0];
    const float* gw1 = (const float*)d_in[1];
    const float* gb1 = (const float*)d_in[2];
    const float* gw2 = (const float*)d_in[3];
    const float* gb2 = (const float*)d_in[4];
    const float* ew1 = (const float*)d_in[5];
    const float* eb1 = (const float*)d_in[6];
    const float* ew2 = (const float*)d_in[7];
    const float* eb2 = (const float*)d_in[8];
    float* out = (float*)d_out;

    // ws layout: gates(256KB) | x16(16MB) | wbuf(8MB) | hbuf(64MB, gh aliases)
    char* ws = (char*)d_ws;
    float* gates = (float*)ws;
    f16* x16  = (f16*)(ws + (256 << 10));
    f16* wbuf = x16 + (size_t)BSZ * IND;
    f16* hbuf = wbuf + (size_t)HID * IND;
    f16* gh   = hbuf;  // alias: gh fully consumed before first expert GEMM

    // 1) x -> fp16
    conv_f32_f16_kernel<<<(BSZ * IND) / (256 * 8), 256, 0, stream>>>(x, x16);

    // 2) gating GEMM1: gh = relu(x @ gw1 + gb1)   [M=8192,N=2048,K=1024]
    transpose_f32_f16_kernel<<<dim3(HGD / 64, IND / 64), 256, 0, stream>>>(gw1, wbuf, IND, HGD);
    gemm3b_kernel<true, false, true, false>
        <<<(HGD / 128) * (BSZ / 256), 512, 0, stream>>>(
            x16, wbuf, gb1, nullptr, gh, BSZ, HGD, IND);

    // 3) gating head + softmax -> gates
    gate_softmax_kernel<<<BSZ / 4, 256, 0, stream>>>(gh, gw2, gb2, gates);

    // 4) experts
    for (int e = 0; e < NE; e++) {
        // h = relu(x @ ew1[e] + eb1[e])   [M=8192,N=4096,K=1024]
        transpose_f32_f16_kernel<<<dim3(HID / 64, IND / 64), 256, 0, stream>>>(
            ew1 + (size_t)e * IND * HID, wbuf, IND, HID);
        gemm3b_kernel<true, false, true, false>
            <<<(HID / 128) * (BSZ / 256), 512, 0, stream>>>(
                x16, wbuf, eb1 + (size_t)e * HID, nullptr, hbuf, BSZ, HID, IND);

        // out (+)= gates[:,e] * (h @ ew2[e] + eb2[e])   [M=8192,N=1024,K=4096]
        transpose_f32_f16_kernel<<<dim3(OUTD / 64, HID / 64), 256, 0, stream>>>(
            ew2 + (size_t)e * HID * OUTD, wbuf, HID, OUTD);
        if (e == 0)
            gemm3b_kernel<false, true, false, false>
                <<<(OUTD / 128) * (BSZ / 256), 512, 0, stream>>>(
                    hbuf, wbuf, eb2 + (size_t)e * OUTD, gates + e, out, BSZ, OUTD, HID);
        else
            gemm3b_kernel<false, true, false, true>
                <<<(OUTD / 128) * (BSZ / 256), 512, 0, stream>>>(
                    hbuf, wbuf, eb2 + (size_t)e * OUTD, gates + e, out, BSZ, OUTD, HID);
    }
}

// Round 6
// 1381.899 us; speedup vs baseline: 1.1407x; 1.1407x over previous
//
#include <hip/hip_runtime.h>

// ---------------------------------------------------------------------------
// MoE forward: gating MLP + 8 dense experts + gate-weighted combine.
// All matmuls via mfma_f32_16x16x32_f16 (fp32 accum).
// r6: algorithm-level fusion. hs[b, e*H+h] = gates[b,e]*relu(x@ew1[e]+eb1[e])
// computed as ONE gemm256 (N=32768, gate folded into epilogue); then
// out = hs @ W2cat + (gates @ eb2) as ONE K=32768 gemmO (bias-dot epilogue).
// Kernels reuse the r4-verified fine-interleaved 8-phase schedules verbatim.
// Falls back to the per-expert r4 path if ws_size < 592MB.
// ---------------------------------------------------------------------------

#define DI __device__ __forceinline__

typedef _Float16 f16;
typedef _Float16 f16x8 __attribute__((ext_vector_type(8)));
typedef float f32x4 __attribute__((ext_vector_type(4)));

constexpr int BSZ  = 8192;
constexpr int IND  = 1024;
constexpr int HID  = 4096;
constexpr int OUTD = 1024;
constexpr int NE   = 8;
constexpr int HGD  = 2048;

// ---------------- fp32 -> fp16 vectorized convert (8 elems/thread) ---------
__global__ __launch_bounds__(256) void conv_f32_f16_kernel(
    const float* __restrict__ in, f16* __restrict__ out)
{
    size_t i = ((size_t)blockIdx.x * 256 + threadIdx.x) * 8;
    const float4* p = (const float4*)(in + i);
    float4 a = p[0], b = p[1];
    f16x8 v = {(f16)a.x, (f16)a.y, (f16)a.z, (f16)a.w,
               (f16)b.x, (f16)b.y, (f16)b.z, (f16)b.w};
    *(f16x8*)(out + i) = v;
}

// ---- transpose+convert: W[K][N] f32 -> Wt[(n)*ldo + ko + k] f16 -----------
__global__ __launch_bounds__(256) void transpose_f32_f16_kernel(
    const float* __restrict__ W, f16* __restrict__ Wt, int K, int N,
    int ldo, int ko)
{
    __shared__ float t[64][65];
    int n0 = blockIdx.x * 64, k0 = blockIdx.y * 64;
    int tx = threadIdx.x & 63, ty = threadIdx.x >> 6;
#pragma unroll
    for (int i = 0; i < 16; i++) {
        int k = i * 4 + ty;
        t[k][tx] = W[(size_t)(k0 + k) * N + n0 + tx];
    }
    __syncthreads();
#pragma unroll
    for (int i = 0; i < 16; i++) {
        int n = i * 4 + ty;
        Wt[(size_t)(n0 + n) * ldo + ko + k0 + tx] = (f16)t[tx][n];
    }
}

// ---------------- async global->LDS (16B per lane, wave-uniform dest) ------
DI void gload_lds16(const void* g, void* l)
{
    typedef const __attribute__((address_space(1))) unsigned int as1_t;
    typedef __attribute__((address_space(3))) unsigned int as3_t;
    __builtin_amdgcn_global_load_lds(
        (as1_t*)(unsigned long long)(__SIZE_TYPE__)g,
        (as3_t*)(unsigned int)(__SIZE_TYPE__)l,
        16, 0, 0);
}

// sync building blocks (rule #18: sched_barrier after lgkmcnt before MFMA)
#define SYNC_HEAD                                                              \
    __builtin_amdgcn_sched_barrier(0);                                         \
    __builtin_amdgcn_s_barrier();                                              \
    asm volatile("s_waitcnt lgkmcnt(0)" ::: "memory");                         \
    __builtin_amdgcn_sched_barrier(0);
#define SYNC_HEAD_T8                                                           \
    __builtin_amdgcn_sched_barrier(0);                                         \
    asm volatile("s_waitcnt lgkmcnt(8)");                                      \
    __builtin_amdgcn_s_barrier();                                              \
    asm volatile("s_waitcnt lgkmcnt(0)" ::: "memory");                         \
    __builtin_amdgcn_sched_barrier(0);
#define SYNC_TAIL                                                              \
    __builtin_amdgcn_sched_barrier(0);                                         \
    __builtin_amdgcn_s_barrier();                                              \
    asm volatile("" ::: "memory");

// ---------------------------------------------------------------------------
// Big kernel: BM=256, BN=256, BK=64, 8 waves 2Mx4N (wave tile 128x64).
// r4-verified schedule. GSCALE: C *= gate[row*NE + col0>>12] (expert = col/H).
// ---------------------------------------------------------------------------
template <bool RELU, bool GSCALE>
__global__ __launch_bounds__(512, 2) void gemm256_kernel(
    const f16* __restrict__ A, const f16* __restrict__ Bt,
    const float* __restrict__ bias, const float* __restrict__ gate,
    f16* __restrict__ Cptr, int M, int N, int K)
{
    constexpr int BM = 256, BN = 256, BK = 64;
    constexpr int AT = BM * BK * 2, BT = BN * BK * 2;   // 32768 each
    __shared__ __align__(16) f16 sA[2][BM * BK];
    __shared__ __align__(16) f16 sB[2][BN * BK];
    const char* sAc = (const char*)sA;
    const char* sBc = (const char*)sB;

    const int tid = threadIdx.x, wid = tid >> 6, lane = tid & 63;
    const int wm = wid >> 2, wn = wid & 3;
    const int nwg = gridDim.x, bid = blockIdx.x;
    const int wg = (bid & 7) * (nwg >> 3) + (bid >> 3);
    const int gx = N / BN;
    const size_t bm = (size_t)(wg / gx) * BM;
    const size_t bn = (size_t)(wg % gx) * BN;

    f32x4 acc[8][4] = {};

    const int rho  = tid >> 3;
    const int slot = (((tid & 7) << 4) ^ (((tid >> 3) & 7) << 4));
    const f16* pA = A  + (bm + rho) * (size_t)K + (slot >> 1);
    const f16* pB = Bt + (bn + rho) * (size_t)K + (slot >> 1);

    auto stA = [&](int b, int q, int T) {
        gload_lds16(pA + ((size_t)q * 64) * K + (size_t)T * BK,
                    (char*)sAc + b * AT + q * 8192 + wid * 1024);
    };
    auto stB = [&](int b, int q, int T) {
        gload_lds16(pB + ((size_t)q * 64) * K + (size_t)T * BK,
                    (char*)sBc + b * BT + q * 8192 + wid * 1024);
    };

    int offA0[8], offB0[4];
#pragma unroll
    for (int f = 0; f < 8; f++) {
        int r = wm * 128 + f * 16 + (lane & 15);
        offA0[f] = r * 128 + ((((lane >> 4) << 4)) ^ ((r & 7) << 4));
    }
#pragma unroll
    for (int f = 0; f < 4; f++) {
        int r = wn * 64 + f * 16 + (lane & 15);
        offB0[f] = r * 128 + ((((lane >> 4) << 4)) ^ ((r & 7) << 4));
    }

    f16x8 av[4][2], bv0[2][2], bv1[2][2];

#define LDAQ(B, MH)                                                            \
    _Pragma("unroll") for (int f = 0; f < 4; f++)                              \
    _Pragma("unroll") for (int kc = 0; kc < 2; kc++)                           \
        av[f][kc] = *(const f16x8*)(sAc + (B) * AT + (offA0[(MH)*4+f] ^ (kc << 6)));
#define LDBH(B, NH, BV)                                                        \
    _Pragma("unroll") for (int f = 0; f < 2; f++)                              \
    _Pragma("unroll") for (int kc = 0; kc < 2; kc++)                           \
        BV[f][kc] = *(const f16x8*)(sBc + (B) * BT + (offB0[(NH)*2+f] ^ (kc << 6)));
#define QUAD(MH, NH, BV)                                                       \
    __builtin_amdgcn_s_setprio(1);                                             \
    _Pragma("unroll") for (int f = 0; f < 4; f++)                              \
    _Pragma("unroll") for (int g = 0; g < 2; g++)                              \
    _Pragma("unroll") for (int kc = 0; kc < 2; kc++)                           \
        acc[(MH)*4+f][(NH)*2+g] = __builtin_amdgcn_mfma_f32_16x16x32_f16(      \
            av[f][kc], BV[g][kc], acc[(MH)*4+f][(NH)*2+g], 0, 0, 0);           \
    __builtin_amdgcn_s_setprio(0);

    const int NT = K / BK, NI = NT / 2;

    stA(0,0,0); stA(0,2,0); stB(0,0,0); stB(0,1,0); stB(0,2,0); stB(0,3,0);
    stA(0,1,0); stA(0,3,0);
    stA(1,0,1); stA(1,2,1); stB(1,0,1); stB(1,1,1); stB(1,2,1); stB(1,3,1);
    asm volatile("s_waitcnt vmcnt(6)");
    __builtin_amdgcn_s_barrier();
    asm volatile("" ::: "memory");

    for (int i = 0; i < NI - 1; ++i) {
        const int t = 2 * i;
        LDAQ(0, 0) LDBH(0, 0, bv0)
        stA(1, 1, t + 1); stA(1, 3, t + 1);
        SYNC_HEAD_T8
        QUAD(0, 0, bv0)
        SYNC_TAIL
        LDBH(0, 1, bv1)
        stA(0, 0, t + 2); stA(0, 2, t + 2);
        SYNC_HEAD
        QUAD(0, 1, bv1)
        SYNC_TAIL
        LDAQ(0, 1)
        stB(0, 0, t + 2); stB(0, 1, t + 2);
        SYNC_HEAD
        QUAD(1, 1, bv1)
        SYNC_TAIL
        stB(0, 2, t + 2); stB(0, 3, t + 2);
        SYNC_HEAD
        QUAD(1, 0, bv0)
        asm volatile("s_waitcnt vmcnt(6)");
        SYNC_TAIL
        LDAQ(1, 0) LDBH(1, 0, bv0)
        stA(0, 1, t + 2); stA(0, 3, t + 2);
        SYNC_HEAD_T8
        QUAD(0, 0, bv0)
        SYNC_TAIL
        LDBH(1, 1, bv1)
        stA(1, 0, t + 3); stA(1, 2, t + 3);
        SYNC_HEAD
        QUAD(0, 1, bv1)
        SYNC_TAIL
        LDAQ(1, 1)
        stB(1, 0, t + 3); stB(1, 1, t + 3);
        SYNC_HEAD
        QUAD(1, 1, bv1)
        SYNC_TAIL
        stB(1, 2, t + 3); stB(1, 3, t + 3);
        SYNC_HEAD
        QUAD(1, 0, bv0)
        asm volatile("s_waitcnt vmcnt(6)");
        SYNC_TAIL
    }
    {   // final iteration (tiles NT-2, NT-1)
        LDAQ(0, 0) LDBH(0, 0, bv0)
        stA(1, 1, NT - 1); stA(1, 3, NT - 1);
        SYNC_HEAD_T8
        QUAD(0, 0, bv0)
        SYNC_TAIL
        LDBH(0, 1, bv1)
        SYNC_HEAD
        QUAD(0, 1, bv1)
        SYNC_TAIL
        LDAQ(0, 1)
        SYNC_HEAD
        QUAD(1, 1, bv1)
        SYNC_TAIL
        SYNC_HEAD
        QUAD(1, 0, bv0)
        asm volatile("s_waitcnt vmcnt(0)");
        SYNC_TAIL
        LDAQ(1, 0) LDBH(1, 0, bv0)
        SYNC_HEAD
        QUAD(0, 0, bv0)
        SYNC_TAIL
        LDBH(1, 1, bv1)
        SYNC_HEAD
        QUAD(0, 1, bv1)
        SYNC_TAIL
        LDAQ(1, 1)
        SYNC_HEAD
        QUAD(1, 1, bv1)
        SYNC_TAIL
        SYNC_HEAD
        QUAD(1, 0, bv0)
        SYNC_TAIL
    }
#undef LDAQ
#undef LDBH
#undef QUAD

    // epilogue: C/D layout col=lane&15, row=(lane>>4)*4+reg
    const size_t row0 = bm + (size_t)wm * 128;
    const int col0 = (int)bn + wn * 64;
    const int c0 = lane & 15, r0 = (lane >> 4) * 4;
#pragma unroll
    for (int fm = 0; fm < 8; fm++)
#pragma unroll
        for (int r = 0; r < 4; r++) {
            const size_t row = row0 + fm * 16 + r0 + r;
            float g = 1.0f;
            if constexpr (GSCALE) g = gate[row * NE + (col0 >> 12)];
#pragma unroll
            for (int n = 0; n < 4; n++) {
                const size_t col = (size_t)col0 + n * 16 + c0;
                float v = acc[fm][n][r] + bias[col];
                if constexpr (RELU) v = fmaxf(v, 0.0f);
                if constexpr (GSCALE) v *= g;
                Cptr[row * (size_t)N + col] = (f16)v;
            }
        }
}

// ---------------------------------------------------------------------------
// OUT kernel: BM=256, BN=128, BK=64, 8 waves 2Mx4N (wave tile 128x32).
// r4-verified schedule. FUSEBIAS: C = acc + sum_e gate[row,e]*eb2[e,col]
// (single write, no gate-mult); else r4 behavior: (acc+bias)*gate, ACCUM RMW.
// ---------------------------------------------------------------------------
template <bool ACCUM, bool FUSEBIAS>
__global__ __launch_bounds__(512, 2) void gemmO_kernel(
    const f16* __restrict__ A, const f16* __restrict__ Bt,
    const float* __restrict__ bias, const float* __restrict__ gate,
    float* __restrict__ Cptr, int M, int N, int K)
{
    constexpr int BM = 256, BN = 128, BK = 64;
    constexpr int AT = BM * BK * 2, BT = BN * BK * 2;   // 32768 / 16384
    __shared__ __align__(16) f16 sA[2][BM * BK];
    __shared__ __align__(16) f16 sB[2][BN * BK];
    const char* sAc = (const char*)sA;
    const char* sBc = (const char*)sB;

    const int tid = threadIdx.x, wid = tid >> 6, lane = tid & 63;
    const int wm = wid >> 2, wn = wid & 3;
    const int nwg = gridDim.x, bid = blockIdx.x;
    const int wg = (bid & 7) * (nwg >> 3) + (bid >> 3);
    const int gx = N / BN;
    const size_t bm = (size_t)(wg / gx) * BM;
    const size_t bn = (size_t)(wg % gx) * BN;

    f32x4 acc[8][2] = {};

    const int rho  = tid >> 3;
    const int slot = (((tid & 7) << 4) ^ (((tid >> 3) & 7) << 4));
    const f16* pA = A  + (bm + rho) * (size_t)K + (slot >> 1);
    const f16* pB = Bt + (bn + rho) * (size_t)K + (slot >> 1);

    auto stA = [&](int b, int q, int T) {
        gload_lds16(pA + ((size_t)q * 64) * K + (size_t)T * BK,
                    (char*)sAc + b * AT + q * 8192 + wid * 1024);
    };
    auto stB = [&](int b, int q, int T) {
        gload_lds16(pB + ((size_t)q * 64) * K + (size_t)T * BK,
                    (char*)sBc + b * BT + q * 8192 + wid * 1024);
    };

    int offA0[8], offB0[2];
#pragma unroll
    for (int f = 0; f < 8; f++) {
        int r = wm * 128 + f * 16 + (lane & 15);
        offA0[f] = r * 128 + ((((lane >> 4) << 4)) ^ ((r & 7) << 4));
    }
#pragma unroll
    for (int f = 0; f < 2; f++) {
        int r = wn * 32 + f * 16 + (lane & 15);
        offB0[f] = r * 128 + ((((lane >> 4) << 4)) ^ ((r & 7) << 4));
    }

    f16x8 av[4], bv[2][2];

#define LDA4(B, MH, KC)                                                        \
    _Pragma("unroll") for (int f = 0; f < 4; f++)                              \
        av[f] = *(const f16x8*)(sAc + (B) * AT + (offA0[(MH)*4+f] ^ ((KC) << 6)));
#define LDBA(B)                                                                \
    _Pragma("unroll") for (int f = 0; f < 2; f++)                              \
    _Pragma("unroll") for (int kc = 0; kc < 2; kc++)                           \
        bv[f][kc] = *(const f16x8*)(sBc + (B) * BT + (offB0[f] ^ (kc << 6)));
#define OCT(MH, KC)                                                            \
    __builtin_amdgcn_s_setprio(1);                                             \
    _Pragma("unroll") for (int f = 0; f < 4; f++)                              \
    _Pragma("unroll") for (int g = 0; g < 2; g++)                              \
        acc[(MH)*4+f][g] = __builtin_amdgcn_mfma_f32_16x16x32_f16(             \
            av[f], bv[g][KC], acc[(MH)*4+f][g], 0, 0, 0);                      \
    __builtin_amdgcn_s_setprio(0);

    const int NT = K / BK, NI = NT / 2;

    stA(0,0,0); stA(0,2,0); stB(0,0,0); stB(0,1,0); stA(0,1,0); stA(0,3,0);
    stA(1,0,1); stA(1,2,1); stB(1,0,1); stB(1,1,1);
    asm volatile("s_waitcnt vmcnt(4)");
    __builtin_amdgcn_s_barrier();
    asm volatile("" ::: "memory");

    for (int i = 0; i < NI - 1; ++i) {
        const int t = 2 * i;
        LDA4(0, 0, 0) LDBA(0)
        stA(1, 1, t + 1); stA(1, 3, t + 1);
        SYNC_HEAD
        OCT(0, 0)
        SYNC_TAIL
        LDA4(0, 0, 1)
        SYNC_HEAD
        OCT(0, 1)
        SYNC_TAIL
        LDA4(0, 1, 0)
        stA(0, 0, t + 2); stA(0, 2, t + 2);
        SYNC_HEAD
        OCT(1, 0)
        SYNC_TAIL
        LDA4(0, 1, 1)
        stB(0, 0, t + 2); stB(0, 1, t + 2);
        SYNC_HEAD
        OCT(1, 1)
        asm volatile("s_waitcnt vmcnt(4)");
        SYNC_TAIL
        LDA4(1, 0, 0) LDBA(1)
        stA(0, 1, t + 2); stA(0, 3, t + 2);
        SYNC_HEAD
        OCT(0, 0)
        SYNC_TAIL
        LDA4(1, 0, 1)
        SYNC_HEAD
        OCT(0, 1)
        SYNC_TAIL
        LDA4(1, 1, 0)
        stA(1, 0, t + 3); stA(1, 2, t + 3);
        SYNC_HEAD
        OCT(1, 0)
        SYNC_TAIL
        LDA4(1, 1, 1)
        stB(1, 0, t + 3); stB(1, 1, t + 3);
        SYNC_HEAD
        OCT(1, 1)
        asm volatile("s_waitcnt vmcnt(4)");
        SYNC_TAIL
    }
    {   // final iteration
        LDA4(0, 0, 0) LDBA(0)
        stA(1, 1, NT - 1); stA(1, 3, NT - 1);
        SYNC_HEAD
        OCT(0, 0)
        SYNC_TAIL
        LDA4(0, 0, 1)
        SYNC_HEAD
        OCT(0, 1)
        SYNC_TAIL
        LDA4(0, 1, 0)
        SYNC_HEAD
        OCT(1, 0)
        SYNC_TAIL
        LDA4(0, 1, 1)
        SYNC_HEAD
        OCT(1, 1)
        asm volatile("s_waitcnt vmcnt(0)");
        SYNC_TAIL
        LDA4(1, 0, 0) LDBA(1)
        SYNC_HEAD
        OCT(0, 0)
        SYNC_TAIL
        LDA4(1, 0, 1)
        SYNC_HEAD
        OCT(0, 1)
        SYNC_TAIL
        LDA4(1, 1, 0)
        SYNC_HEAD
        OCT(1, 0)
        SYNC_TAIL
        LDA4(1, 1, 1)
        SYNC_HEAD
        OCT(1, 1)
        SYNC_TAIL
    }
#undef LDA4
#undef LDBA
#undef OCT

    const size_t row0 = bm + (size_t)wm * 128;
    const int col0 = (int)bn + wn * 32;
    const int c0 = lane & 15, r0 = (lane >> 4) * 4;

    if constexpr (FUSEBIAS) {
        // eb2[e, col] invariant across rows: hoist 2x8 loads per thread
        float e2[2][NE];
#pragma unroll
        for (int n = 0; n < 2; n++) {
            const int col = col0 + n * 16 + c0;
#pragma unroll
            for (int e = 0; e < NE; e++) e2[n][e] = bias[e * OUTD + col];
        }
#pragma unroll
        for (int fm = 0; fm < 8; fm++)
#pragma unroll
            for (int r = 0; r < 4; r++) {
                const size_t row = row0 + fm * 16 + r0 + r;
                const float* gr = gate + row * NE;
                float gv[NE];
#pragma unroll
                for (int e = 0; e < NE; e++) gv[e] = gr[e];
#pragma unroll
                for (int n = 0; n < 2; n++) {
                    float bb = 0.f;
#pragma unroll
                    for (int e = 0; e < NE; e++) bb = fmaf(gv[e], e2[n][e], bb);
                    const size_t col = (size_t)col0 + n * 16 + c0;
                    Cptr[row * (size_t)N + col] = acc[fm][n][r] + bb;
                }
            }
    } else {
#pragma unroll
        for (int fm = 0; fm < 8; fm++)
#pragma unroll
            for (int r = 0; r < 4; r++) {
                const size_t row = row0 + fm * 16 + r0 + r;
                const float g = gate[row * NE];
#pragma unroll
                for (int n = 0; n < 2; n++) {
                    const size_t col = (size_t)col0 + n * 16 + c0;
                    float v = (acc[fm][n][r] + bias[col]) * g;
                    float* p = Cptr + row * (size_t)N + col;
                    *p = ACCUM ? (*p + v) : v;
                }
            }
    }
}

// --------- gating head: logits = gh@gw2 + gb2, softmax -> gates fp32 -------
__global__ __launch_bounds__(256) void gate_softmax_kernel(
    const f16* __restrict__ gh, const float* __restrict__ gw2,
    const float* __restrict__ gb2, float* __restrict__ gates)
{
    const int row  = blockIdx.x * 4 + (threadIdx.x >> 6);
    const int lane = threadIdx.x & 63;
    const f16* r = gh + (size_t)row * HGD;
    float acc[NE] = {};
    for (int k = lane; k < HGD; k += 64) {
        float h = (float)r[k];
        const float* w = gw2 + (size_t)k * NE;
#pragma unroll
        for (int e = 0; e < NE; e++) acc[e] = fmaf(h, w[e], acc[e]);
    }
#pragma unroll
    for (int off = 32; off > 0; off >>= 1)
#pragma unroll
        for (int e = 0; e < NE; e++) acc[e] += __shfl_down(acc[e], off, 64);
    if (lane == 0) {
        float l[NE], m = -1e30f;
#pragma unroll
        for (int e = 0; e < NE; e++) { l[e] = acc[e] + gb2[e]; m = fmaxf(m, l[e]); }
        float s = 0.f;
#pragma unroll
        for (int e = 0; e < NE; e++) { l[e] = expf(l[e] - m); s += l[e]; }
        float inv = 1.0f / s;
#pragma unroll
        for (int e = 0; e < NE; e++) gates[(size_t)row * NE + e] = l[e] * inv;
    }
}

// ---------------------------------------------------------------------------
extern "C" void kernel_launch(void* const* d_in, const int* in_sizes, int n_in,
                              void* d_out, int out_size, void* d_ws, size_t ws_size,
                              hipStream_t stream)
{
    const float* x   = (const float*)d_in[0];
    const float* gw1 = (const float*)d_in[1];
    const float* gb1 = (const float*)d_in[2];
    const float* gw2 = (const float*)d_in[3];
    const float* gb2 = (const float*)d_in[4];
    const float* ew1 = (const float*)d_in[5];
    const float* eb1 = (const float*)d_in[6];
    const float* ew2 = (const float*)d_in[7];
    const float* eb2 = (const float*)d_in[8];
    float* out = (float*)d_out;

    constexpr int EH = NE * HID;                       // 32768
    const size_t need_fused =
        (size_t)(256 << 10)                            // gates
        + (size_t)BSZ * IND * 2                        // x16       16MB
        + (size_t)OUTD * EH * 2                        // wcat      64MB
        + (size_t)BSZ * EH * 2;                        // hs       512MB

    char* ws = (char*)d_ws;
    float* gates = (float*)ws;
    f16* x16 = (f16*)(ws + (256 << 10));

    // 1) x -> fp16 (both paths)
    conv_f32_f16_kernel<<<(BSZ * IND) / (256 * 8), 256, 0, stream>>>(x, x16);

    if (ws_size >= need_fused) {
        // ---------------- fused path ----------------
        f16* wcat = x16 + (size_t)BSZ * IND;           // 64MB: w1cat then w2cat
        f16* hs   = wcat + (size_t)OUTD * EH;          // 512MB
        f16* gh   = hs;                                // 32MB alias, dead early

        // gating: gh = relu(x @ gw1 + gb1)
        transpose_f32_f16_kernel<<<dim3(HGD / 64, IND / 64), 256, 0, stream>>>(
            gw1, wcat, IND, HGD, IND, 0);
        gemm256_kernel<true, false>
            <<<(HGD / 256) * (BSZ / 256), 512, 0, stream>>>(
                x16, wcat, gb1, nullptr, gh, BSZ, HGD, IND);
        gate_softmax_kernel<<<BSZ / 4, 256, 0, stream>>>(gh, gw2, gb2, gates);

        // W1cat[e*H+n, k] = ew1[e,k,n]
        for (int e = 0; e < NE; e++)
            transpose_f32_f16_kernel<<<dim3(HID / 64, IND / 64), 256, 0, stream>>>(
                ew1 + (size_t)e * IND * HID, wcat + (size_t)e * HID * IND,
                IND, HID, IND, 0);
        // hs = gates * relu(x @ W1cat + eb1)   [M=8192, N=32768, K=1024]
        gemm256_kernel<true, true>
            <<<(EH / 256) * (BSZ / 256), 512, 0, stream>>>(
                x16, wcat, eb1, gates, hs, BSZ, EH, IND);

        // W2cat[o, e*H+h] = ew2[e,h,o]
        for (int e = 0; e < NE; e++)
            transpose_f32_f16_kernel<<<dim3(OUTD / 64, HID / 64), 256, 0, stream>>>(
                ew2 + (size_t)e * HID * OUTD, wcat, HID, OUTD, EH, e * HID);
        // out = hs @ W2cat + gates @ eb2       [M=8192, N=1024, K=32768]
        gemmO_kernel<false, true>
            <<<(OUTD / 128) * (BSZ / 256), 512, 0, stream>>>(
                hs, wcat, eb2, gates, out, BSZ, OUTD, EH);
    } else {
        // ---------------- r4 per-expert fallback ----------------
        f16* wbuf = x16 + (size_t)BSZ * IND;
        f16* hbuf = wbuf + (size_t)HID * IND;
        f16* gh   = hbuf;

        transpose_f32_f16_kernel<<<dim3(HGD / 64, IND / 64), 256, 0, stream>>>(
            gw1, wbuf, IND, HGD, IND, 0);
        gemm256_kernel<true, false>
            <<<(HGD / 256) * (BSZ / 256), 512, 0, stream>>>(
                x16, wbuf, gb1, nullptr, gh, BSZ, HGD, IND);
        gate_softmax_kernel<<<BSZ / 4, 256, 0, stream>>>(gh, gw2, gb2, gates);

        for (int e = 0; e < NE; e++) {
            transpose_f32_f16_kernel<<<dim3(HID / 64, IND / 64), 256, 0, stream>>>(
                ew1 + (size_t)e * IND * HID, wbuf, IND, HID, IND, 0);
            gemm256_kernel<true, false>
                <<<(HID / 256) * (BSZ / 256), 512, 0, stream>>>(
                    x16, wbuf, eb1 + (size_t)e * HID, nullptr, hbuf, BSZ, HID, IND);

            transpose_f32_f16_kernel<<<dim3(OUTD / 64, HID / 64), 256, 0, stream>>>(
                ew2 + (size_t)e * HID * OUTD, wbuf, HID, OUTD, HID, 0);
            if (e == 0)
                gemmO_kernel<false, false>
                    <<<(OUTD / 128) * (BSZ / 256), 512, 0, stream>>>(
                        hbuf, wbuf, eb2 + (size_t)e * OUTD, gates + e, out,
                        BSZ, OUTD, HID);
            else
                gemmO_kernel<true, false>
                    <<<(OUTD / 128) * (BSZ / 256), 512, 0, stream>>>(
                        hbuf, wbuf, eb2 + (size_t)e * OUTD, gates + e, out,
                        BSZ, OUTD, HID);
        }
    }
}